// Round 7
// baseline (343.404 us; speedup 1.0000x reference)
//
#include <hip/hip_runtime.h>
#include <math.h>

#define NBLK 256
#define BATCH 256
#define CLS 500
#define T_TEMP_ 10.0f
#define THRESH_ 0.86602540378443864676f
#define NEGV -9.0e15f

typedef __attribute__((ext_vector_type(8))) short short8;
typedef __attribute__((ext_vector_type(8))) unsigned short u16x8;
typedef __attribute__((ext_vector_type(4))) unsigned short u16x4;
typedef __attribute__((ext_vector_type(4))) float f32x4;
typedef __attribute__((ext_vector_type(2))) float f32x2;

static __device__ __forceinline__ unsigned short f2bf(float x) {
    unsigned int u = __builtin_bit_cast(unsigned int, x);
    u += 0x7fff + ((u >> 16) & 1);
    return (unsigned short)(u >> 16);
}
static __device__ __forceinline__ float bf2f(unsigned short v) {
    return __builtin_bit_cast(float, (unsigned int)v << 16);
}
static __device__ __forceinline__ u16x8 pack8(const float4& a, const float4& b) {
    u16x8 o;
    o[0] = f2bf(a.x); o[1] = f2bf(a.y); o[2] = f2bf(a.z); o[3] = f2bf(a.w);
    o[4] = f2bf(b.x); o[5] = f2bf(b.y); o[6] = f2bf(b.z); o[7] = f2bf(b.w);
    return o;
}

struct MegaP {
    const float *imgf, *attrs, *attg, *imgw, *semw, *semb, *fcw, *fcb;
    float* out;
    unsigned short *attr_bf, *imgf_bf, *attgT, *imgwT, *semwT, *gn_bf, *atto_bf, *hidP;
    float *gpart, *sim, *outP;
    unsigned int* bar;
};

// ---- device-scope grid barrier (all NBLK blocks co-resident by construction) ----
static __device__ __forceinline__ void grid_barrier(unsigned int* bar) {
    __syncthreads();
    if (threadIdx.x == 0) {
        __threadfence();
        unsigned int* cnt = bar;
        unsigned int* gen = bar + 1;
        unsigned int g = __hip_atomic_load(gen, __ATOMIC_ACQUIRE, __HIP_MEMORY_SCOPE_AGENT);
        unsigned int a = __hip_atomic_fetch_add(cnt, 1u, __ATOMIC_ACQ_REL, __HIP_MEMORY_SCOPE_AGENT);
        if (a + 1 == NBLK) {
            __hip_atomic_store(cnt, 0u, __ATOMIC_RELAXED, __HIP_MEMORY_SCOPE_AGENT);
            __hip_atomic_store(gen, g + 1u, __ATOMIC_RELEASE, __HIP_MEMORY_SCOPE_AGENT);
        } else {
            while (__hip_atomic_load(gen, __ATOMIC_ACQUIRE, __HIP_MEMORY_SCOPE_AGENT) == g)
                __builtin_amdgcn_s_sleep(2);
        }
        __threadfence();
    }
    __syncthreads();
}

// ---- bf16 MFMA GEMM tile: C[64x128] += A[64xK-slice] @ B[N,K]^T slice ----
// (verbatim structure from the round-5-verified mfma_gemm_bf)
static __device__ __forceinline__ void gemm_tile(
    const unsigned short* __restrict__ A, int ar0, int alim,
    const unsigned short* __restrict__ B, int n0, int N,
    int K, int k0, int klen,
    float* __restrict__ Cf, unsigned short* __restrict__ Cbf, size_t coff,
    int M, int orow0base,
    unsigned short* AsP, unsigned short* BsP)
{
    const int t = threadIdx.x;
    const int w = t >> 6, lane = t & 63;
    const int wr = w >> 1, wc = w & 1;
    const int fr = lane & 15, kg = lane >> 4;
    const int a_row = t >> 2, a_k = (t & 3) * 8;
    const int b_row = t >> 1, b_k = (t & 1) * 16;
    const int gra = ar0 + a_row;
    const int grb = n0 + b_row;
    const bool va = gra < alim;
    const bool vb = grb < N;
    const size_t abase = (size_t)gra * K + a_k;
    const size_t bbase = (size_t)grb * K + b_k;

    u16x8 zz = {0,0,0,0,0,0,0,0};
    u16x8 pa = zz, pb0 = zz, pb1 = zz;
    if (va) pa = *(const u16x8*)&A[abase + k0];
    if (vb) { pb0 = *(const u16x8*)&B[bbase + k0]; pb1 = *(const u16x8*)&B[bbase + k0 + 8]; }

    f32x4 acc[2][4];
    #pragma unroll
    for (int i = 0; i < 2; ++i)
        #pragma unroll
        for (int j = 0; j < 4; ++j) acc[i][j] = (f32x4){0.f, 0.f, 0.f, 0.f};

    for (int kb = k0; kb < k0 + klen; kb += 32) {
        *(u16x8*)(AsP + a_row * 40 + a_k) = pa;
        *(u16x8*)(BsP + b_row * 40 + b_k) = pb0;
        *(u16x8*)(BsP + b_row * 40 + b_k + 8) = pb1;
        __syncthreads();

        const int kn = kb + 32;
        if (kn < k0 + klen) {
            if (va) pa = *(const u16x8*)&A[abase + kn];
            if (vb) { pb0 = *(const u16x8*)&B[bbase + kn]; pb1 = *(const u16x8*)&B[bbase + kn + 8]; }
        }

        short8 af[2], bfr[4];
        #pragma unroll
        for (int i = 0; i < 2; ++i)
            af[i] = *(short8*)(AsP + (wr * 32 + i * 16 + fr) * 40 + kg * 8);
        #pragma unroll
        for (int j = 0; j < 4; ++j)
            bfr[j] = *(short8*)(BsP + (wc * 64 + j * 16 + fr) * 40 + kg * 8);
        #pragma unroll
        for (int i = 0; i < 2; ++i)
            #pragma unroll
            for (int j = 0; j < 4; ++j)
                acc[i][j] = __builtin_amdgcn_mfma_f32_16x16x32_bf16(
                    af[i], bfr[j], acc[i][j], 0, 0, 0);
        __syncthreads();
    }

    const int orow0 = orow0base + wr * 32, ocol0 = n0 + wc * 64;
    if (Cbf) {
        unsigned short* Cw = Cbf + coff;
        #pragma unroll
        for (int i = 0; i < 2; ++i) {
            const int r0 = orow0 + i * 16 + kg * 4;
            #pragma unroll
            for (int j = 0; j < 4; ++j) {
                const int cc = ocol0 + j * 16 + fr;
                if (cc >= N) continue;
                #pragma unroll
                for (int r = 0; r < 4; ++r) {
                    const int rr = r0 + r;
                    if (rr < M) Cw[(size_t)rr * N + cc] = f2bf(acc[i][j][r]);
                }
            }
        }
    } else {
        float* Cw = Cf + coff;
        #pragma unroll
        for (int i = 0; i < 2; ++i) {
            const int r0 = orow0 + i * 16 + kg * 4;
            #pragma unroll
            for (int j = 0; j < 4; ++j) {
                const int cc = ocol0 + j * 16 + fr;
                if (cc >= N) continue;
                #pragma unroll
                for (int r = 0; r < 4; ++r) {
                    const int rr = r0 + r;
                    if (rr < M) Cw[(size_t)rr * N + cc] = acc[i][j][r];
                }
            }
        }
    }
}

__global__ __launch_bounds__(256) void mega_kernel(MegaP p)
{
    __shared__ __align__(16) char pool[35840];
    const int t = threadIdx.x;
    const int bid = blockIdx.x;
    unsigned short* As = (unsigned short*)pool;
    unsigned short* Bs = As + 64 * 40;

    // ================= P0: convert + transpose to bf16 =================
    for (int it = bid; it < 954; it += NBLK) {
        if (it < 378) {
            const float* s; unsigned short* d; int idx;
            if (it < 250) { s = p.attrs; d = p.attr_bf; idx = it * 2048 + t * 8; }
            else          { s = p.imgf;  d = p.imgf_bf; idx = (it - 250) * 2048 + t * 8; }
            float4 v0 = *(const float4*)&s[idx];
            float4 v1 = *(const float4*)&s[idx + 4];
            *(u16x8*)&d[idx] = pack8(v0, v1);
        } else {
            int b2 = it - 378;
            const float* s; unsigned short* d; int Csz;
            if (b2 < 64)       { s = p.attg; d = p.attgT; Csz = 256; }
            else if (b2 < 320) { b2 -= 64;  s = p.imgw; d = p.imgwT; Csz = 1024; }
            else               { b2 -= 320; s = p.semw; d = p.semwT; Csz = 1024; }
            const int tiles_c = Csz >> 6;
            const int tr = b2 / tiles_c, tc2 = b2 % tiles_c;
            unsigned short* tb = (unsigned short*)pool;
            __syncthreads();   // guard tb reuse across loop iterations
            {
                const int r = t >> 2, cq = (t & 3) * 16;
                const float* sp = &s[(size_t)(tr * 64 + r) * Csz + tc2 * 64 + cq];
                float4 v0 = *(const float4*)(sp);
                float4 v1 = *(const float4*)(sp + 4);
                float4 v2 = *(const float4*)(sp + 8);
                float4 v3 = *(const float4*)(sp + 12);
                *(u16x8*)&tb[r * 72 + cq]     = pack8(v0, v1);
                *(u16x8*)&tb[r * 72 + cq + 8] = pack8(v2, v3);
            }
            __syncthreads();
            {
                const int c = t >> 2, r0 = (t & 3) * 16;
                u16x8 o0, o1;
                #pragma unroll
                for (int i = 0; i < 8; ++i) { o0[i] = tb[(r0 + i) * 72 + c]; o1[i] = tb[(r0 + 8 + i) * 72 + c]; }
                unsigned short* q = &d[(size_t)(tc2 * 64 + c) * 1024 + tr * 64 + r0];
                *(u16x8*)q = o0;
                *(u16x8*)(q + 8) = o1;
            }
        }
    }
    grid_barrier(p.bar);

    // ================= P1: g = attrs @ att_g^T  [500,256], split-K 16 =================
    {
        const int tile = bid >> 4, split = bid & 15;
        const int mt = tile >> 1, nt = tile & 1;
        gemm_tile(p.attr_bf, mt * 64, 500, p.attgT, nt * 128, 256,
                  1024, split * 64, 64,
                  p.gpart, nullptr, (size_t)split * (CLS * 256), 500, mt * 64, As, Bs);
    }
    grid_barrier(p.bar);

    // ================= P2: reduce 16 partials + row-normalize -> gn bf16 =================
    if (bid < 250) {
        float* red = (float*)pool;
        for (int r = 0; r < 2; ++r) {
            const int c = bid * 2 + r;
            float v = 0.f;
            #pragma unroll
            for (int z = 0; z < 16; ++z) v += p.gpart[(size_t)z * (CLS * 256) + c * 256 + t];
            float ss = v * v;
            #pragma unroll
            for (int off = 32; off >= 1; off >>= 1) ss += __shfl_down(ss, off);
            const int wave = t >> 6, lane = t & 63;
            if (lane == 0) red[wave] = ss;
            __syncthreads();
            const float tot = red[0] + red[1] + red[2] + red[3];
            p.gn_bf[c * 256 + t] = f2bf(v * (1.f / sqrtf(tot)));
            __syncthreads();   // guard red reuse
        }
    }
    grid_barrier(p.bar);

    // ================= P3: sim = gn @ gn^T  [500,500] =================
    if (bid < 32) {
        const int mt = bid >> 2, nt = bid & 3;
        gemm_tile(p.gn_bf, mt * 64, 500, p.gn_bf, nt * 128, 500,
                  256, 0, 256,
                  p.sim, nullptr, 0, 500, mt * 64, As, Bs);
    }
    grid_barrier(p.bar);

    // ================= P4: masked softmax + sparse accumulate -> att_outs bf16 =================
    for (int c = bid; c < CLS; c += NBLK) {
        float* p_s  = (float*)pool;            // [512]
        float* redm = (float*)(pool + 2048);   // [4]
        float* reds = (float*)(pool + 2080);   // [4]

        const float d0 = p.sim[(size_t)c * CLS + t];
        const float d1 = (t + 256 < CLS) ? p.sim[(size_t)c * CLS + t + 256] : NEGV;

        float vmax = fmaxf((d0 > THRESH_) ? d0 : NEGV, (d1 > THRESH_) ? d1 : NEGV);
        #pragma unroll
        for (int off = 32; off >= 1; off >>= 1) vmax = fmaxf(vmax, __shfl_down(vmax, off));
        const int wave = t >> 6, lane = t & 63;
        if (lane == 0) redm[wave] = vmax;
        __syncthreads();
        const float m = fmaxf(fmaxf(redm[0], redm[1]), fmaxf(redm[2], redm[3]));

        const float p0 = (d0 > THRESH_) ? expf(T_TEMP_ * (d0 - m)) : 0.f;
        const float p1 = (d1 > THRESH_) ? expf(T_TEMP_ * (d1 - m)) : 0.f;
        p_s[t] = p0;
        p_s[t + 256] = p1;
        float vsum = p0 + p1;
        #pragma unroll
        for (int off = 32; off >= 1; off >>= 1) vsum += __shfl_down(vsum, off);
        if (lane == 0) reds[wave] = vsum;
        __syncthreads();
        const float inv = 1.f / (reds[0] + reds[1] + reds[2] + reds[3]);

        float acc[4] = {0.f, 0.f, 0.f, 0.f};
        for (int base = 0; base < 512; base += 64) {
            const float pv_l = p_s[base + lane];
            unsigned long long mask = __ballot(pv_l > 0.f);
            while (mask) {
                const int l = __ffsll((long long)mask) - 1;
                mask &= mask - 1;
                const int c2 = base + l;
                const float pv = p_s[c2];
                const float* ar = &p.attrs[(size_t)c2 * 1024 + t];
                #pragma unroll
                for (int j = 0; j < 4; ++j) acc[j] += pv * ar[256 * j];
            }
        }
        #pragma unroll
        for (int j = 0; j < 4; ++j)
            p.atto_bf[(size_t)c * 1024 + t + 256 * j] = f2bf(acc[j] * inv);
        __syncthreads();   // guard p_s reuse
    }
    grid_barrier(p.bar);

    // ================= P5: hid[756,1024] bf16 partials, split-K 2 =================
    if (bid < 192) {
        const int tile = bid >> 1, split = bid & 1;
        const int mt = tile >> 3, nt = tile & 7;
        const unsigned short* A; const unsigned short* B; int ar0, alim;
        if (mt < 4) { A = p.imgf_bf; ar0 = mt * 64;       alim = 256; B = p.imgwT; }
        else        { A = p.atto_bf; ar0 = (mt - 4) * 64; alim = 500; B = p.semwT; }
        gemm_tile(A, ar0, alim, B, nt * 128, 1024,
                  1024, split * 512, 512,
                  nullptr, p.hidP, (size_t)split * (756 * 1024), 756, mt * 64, As, Bs);
    }
    grid_barrier(p.bar);

    // ================= P6: fused relu-reduction -> outP[8][256][500] =================
    {
        const int bx = bid & 3, by = (bid >> 2) & 7, bz = bid >> 5;
        const int b0 = bx * 64, c0 = by * 64, h0 = bz * 128;
        float* imgs = (float*)pool;               // [64][68]
        float* sems = (float*)(pool + 17408);     // [64][68]
        float* fcs  = (float*)(pool + 34816);     // [128]
        const size_t pstride = (size_t)756 * 1024;
        const int tb_ = t >> 4, tc_ = t & 15;

        if (t < 32) *(f32x4*)&fcs[t * 4] = *(const f32x4*)&p.fcw[h0 + t * 4];

        f32x2 acc2[4][4];
        #pragma unroll
        for (int i = 0; i < 4; ++i)
            #pragma unroll
            for (int j = 0; j < 4; ++j) acc2[i][j] = (f32x2){0.f, 0.f};

        for (int hs = 0; hs < 2; ++hs) {
            const int hb = h0 + hs * 64;
            #pragma unroll
            for (int i = 0; i < 4; ++i) {
                const int row = (t >> 4) + 16 * i;
                const int col = (t & 15) * 4;
                f32x4 iv = {0.f, 0.f, 0.f, 0.f};
                const unsigned short* pi = &p.hidP[(size_t)(b0 + row) * 1024 + hb + col];
                #pragma unroll
                for (int z = 0; z < 2; ++z) {
                    u16x4 vz = *(const u16x4*)(pi + (size_t)z * pstride);
                    iv[0] += bf2f(vz[0]); iv[1] += bf2f(vz[1]);
                    iv[2] += bf2f(vz[2]); iv[3] += bf2f(vz[3]);
                }
                *(f32x4*)&imgs[row * 68 + col] = iv;

                f32x4 sv = {0.f, 0.f, 0.f, 0.f};
                if (c0 + row < CLS) {
                    const unsigned short* ps2 = &p.hidP[(size_t)(256 + c0 + row) * 1024 + hb + col];
                    #pragma unroll
                    for (int z = 0; z < 2; ++z) {
                        u16x4 vz = *(const u16x4*)(ps2 + (size_t)z * pstride);
                        sv[0] += bf2f(vz[0]); sv[1] += bf2f(vz[1]);
                        sv[2] += bf2f(vz[2]); sv[3] += bf2f(vz[3]);
                    }
                    const f32x4 bb = *(const f32x4*)&p.semb[hb + col];
                    sv += bb;
                }
                *(f32x4*)&sems[row * 68 + col] = sv;
            }
            __syncthreads();

            #pragma unroll
            for (int h4 = 0; h4 < 16; ++h4) {
                f32x4 ia[4], sa[4];
                #pragma unroll
                for (int i = 0; i < 4; ++i) ia[i] = *(f32x4*)&imgs[(tb_ + 16 * i) * 68 + h4 * 4];
                #pragma unroll
                for (int j = 0; j < 4; ++j) sa[j] = *(f32x4*)&sems[(tc_ + 16 * j) * 68 + h4 * 4];
                const f32x4 wv = *(const f32x4*)&fcs[hs * 64 + h4 * 4];
                #pragma unroll
                for (int e2 = 0; e2 < 2; ++e2) {
                    const f32x2 w2 = {wv[2 * e2], wv[2 * e2 + 1]};
                    f32x2 ia2[4], sa2[4];
                    #pragma unroll
                    for (int i = 0; i < 4; ++i) ia2[i] = (f32x2){ia[i][2 * e2], ia[i][2 * e2 + 1]};
                    #pragma unroll
                    for (int j = 0; j < 4; ++j) sa2[j] = (f32x2){sa[j][2 * e2], sa[j][2 * e2 + 1]};
                    #pragma unroll
                    for (int i = 0; i < 4; ++i)
                        #pragma unroll
                        for (int j = 0; j < 4; ++j) {
                            f32x2 s = ia2[i] + sa2[j];
                            s = __builtin_elementwise_max(s, (f32x2){0.f, 0.f});
                            acc2[i][j] += s * w2;
                        }
                }
            }
            __syncthreads();
        }

        #pragma unroll
        for (int i = 0; i < 4; ++i) {
            const int b = b0 + tb_ + 16 * i;
            #pragma unroll
            for (int j = 0; j < 4; ++j) {
                const int cc = c0 + tc_ + 16 * j;
                if (cc < CLS)
                    p.outP[((size_t)bz * BATCH + b) * CLS + cc] = acc2[i][j][0] + acc2[i][j][1];
            }
        }
    }
    grid_barrier(p.bar);

    // ================= P7: finalize =================
    {
        int idx = bid * 256 + t;
        #pragma unroll
        for (int r = 0; r < 2; ++r, idx += 65536) {
            if (idx < BATCH * CLS) {
                float s = p.fcb[0];
                #pragma unroll
                for (int nh = 0; nh < 8; ++nh)
                    s += p.outP[(size_t)nh * (BATCH * CLS) + idx];
                p.out[idx] = s;
            }
        }
    }
}

extern "C" void kernel_launch(void* const* d_in, const int* in_sizes, int n_in,
                              void* d_out, int out_size, void* d_ws, size_t ws_size,
                              hipStream_t stream)
{
    MegaP P;
    P.imgf  = (const float*)d_in[0];
    P.attrs = (const float*)d_in[1];
    P.attg  = (const float*)d_in[3];
    P.imgw  = (const float*)d_in[4];
    P.semw  = (const float*)d_in[5];
    P.semb  = (const float*)d_in[6];
    P.fcw   = (const float*)d_in[7];
    P.fcb   = (const float*)d_in[8];
    P.out   = (float*)d_out;

    char* ws = (char*)d_ws;
    size_t off = 256;   // bar occupies [0,256)
    auto alloc = [&](size_t b) { size_t o = off; off = (off + b + 255) & ~(size_t)255; return o; };

    P.bar     = (unsigned int*)ws;
    P.attr_bf = (unsigned short*)(ws + alloc((size_t)500 * 1024 * 2));
    P.imgf_bf = (unsigned short*)(ws + alloc((size_t)256 * 1024 * 2));
    P.attgT   = (unsigned short*)(ws + alloc((size_t)256 * 1024 * 2));
    P.imgwT   = (unsigned short*)(ws + alloc((size_t)1024 * 1024 * 2));
    P.semwT   = (unsigned short*)(ws + alloc((size_t)1024 * 1024 * 2));
    P.gn_bf   = (unsigned short*)(ws + alloc((size_t)500 * 256 * 2));
    P.atto_bf = (unsigned short*)(ws + alloc((size_t)500 * 1024 * 2));
    P.hidP    = (unsigned short*)(ws + alloc((size_t)2 * 756 * 1024 * 2));
    P.gpart   = (float*)(ws + alloc((size_t)16 * CLS * 256 * 4));
    P.sim     = (float*)(ws + alloc((size_t)CLS * CLS * 4));
    P.outP    = (float*)(ws + alloc((size_t)8 * BATCH * CLS * 4));

    // zero the grid-barrier state (captured into the graph; runs every replay)
    hipMemsetAsync(d_ws, 0, 256, stream);
    mega_kernel<<<NBLK, 256, 0, stream>>>(P);
}